// Round 4
// baseline (919.149 us; speedup 1.0000x reference)
//
#include <hip/hip_runtime.h>

#define NPIX (512*512)

// ---------------------------------------------------------------------------
// Init kernel: coef[path][a][b][kq] = 0.5 * tp_w * Cr  (padded k-runs: 12/16).
// Path offsets (floats): {0,972,2268,3672,5544,6948,8820,10848}, 13552 total.
// path index p: la = p&4?6:4, lb = p&2?6:4, lc = p&1?6:4.
// layout per path: [a (2la+1)][b (2lb+1)][kq (ncp=12|16)], pads (c>=nc) are 0.
// ---------------------------------------------------------------------------

static __device__ __forceinline__ int qcol(int l, int c, int* row, double* re, double* im) {
  const double S = 0.70710678118654752440;
  int p = c - l;
  if (p == 0) { row[0] = l; re[0] = 1.0; im[0] = 0.0; return 1; }
  if (p > 0) {
    row[0] = l - p; re[0] = S;                 im[0] = 0.0;
    row[1] = l + p; re[1] = (p & 1) ? -S : S;  im[1] = 0.0;
    return 2;
  }
  int a = -p;
  row[0] = l - a; re[0] = 0.0; im[0] = -S;
  row[1] = l + a; re[1] = 0.0; im[1] = (a & 1) ? -S : S;
  return 2;
}

__global__ void w3j_init(const float* __restrict__ tpw, float* __restrict__ coef) {
  __shared__ double sC[13*13*13];
  __shared__ double sfact[20];
  const int p = blockIdx.x;
  const int la = (p & 4) ? 6 : 4, lb = (p & 2) ? 6 : 4, lc = (p & 1) ? 6 : 4;
  const int na = 2*la+1, nb = 2*lb+1, nc = 2*lc+1, ncp = (nc + 3) & ~3;
  if (threadIdx.x == 0) {
    double f = 1.0; sfact[0] = 1.0;
    for (int i = 1; i < 20; ++i) { f *= (double)i; sfact[i] = f; }
  }
  int off = 0;
  for (int q = 0; q < p; ++q)
    off += ((q&4)?13:9) * ((q&2)?13:9) * ((q&1)?16:12);
  for (int e = threadIdx.x; e < na*nb*nc; e += blockDim.x) sC[e] = 0.0;
  __syncthreads();
  for (int e = threadIdx.x; e < na*nb; e += blockDim.x) {
    int i = e / nb, j = e % nb;
    int m1 = i - la, m2 = j - lb, m3 = m1 + m2;
    if (m3 < -lc || m3 > lc) continue;
    double pre = sqrt((2.0*lc + 1.0) * sfact[lc+la-lb] * sfact[lc-la+lb] * sfact[la+lb-lc] / sfact[la+lb+lc+1]);
    pre *= sqrt(sfact[lc+m3]*sfact[lc-m3]*sfact[la-m1]*sfact[la+m1]*sfact[lb-m2]*sfact[lb+m2]);
    double s = 0.0;
    for (int k = 0; k <= la + lb - lc; ++k) {
      int d2 = la - m1 - k, d3 = lb + m2 - k, d4 = lc - lb + m1 + k, d5 = lc - la - m2 + k;
      if (d2 < 0 || d3 < 0 || d4 < 0 || d5 < 0) continue;
      s += ((k & 1) ? -1.0 : 1.0) /
           (sfact[k]*sfact[la+lb-lc-k]*sfact[d2]*sfact[d3]*sfact[d4]*sfact[d5]);
    }
    sC[(i*nb + j)*nc + (lc + m3)] = pre * s;
  }
  __syncthreads();
  const double PH = (((la/2)&1)?-1.0:1.0)*(((lb/2)&1)?-1.0:1.0)*(((lc/2)&1)?-1.0:1.0);
  const double scale = 0.5 * (double)tpw[p] * PH;
  for (int e = threadIdx.x; e < na*nb*ncp; e += blockDim.x) {
    int a = e / (nb*ncp), rem = e % (nb*ncp), b = rem / ncp, c = rem % ncp;
    float val = 0.0f;
    if (c < nc) {
      int r1[2]; double u1r[2], u1i[2]; int n1 = qcol(la, a, r1, u1r, u1i);
      int r2[2]; double u2r[2], u2i[2]; int n2 = qcol(lb, b, r2, u2r, u2i);
      int r3[2]; double u3r[2], u3i[2]; int n3 = qcol(lc, c, r3, u3r, u3i);
      double acc = 0.0;
      for (int u = 0; u < n1; ++u)
        for (int v = 0; v < n2; ++v) {
          double Rr = u1r[u]*u2r[v] - u1i[u]*u2i[v];
          double Ri = u1r[u]*u2i[v] + u1i[u]*u2r[v];
          for (int w = 0; w < n3; ++w) {
            double cv = sC[(r1[u]*nb + r2[v])*nc + r3[w]];
            acc += (Rr*u3r[w] + Ri*u3i[w]) * cv;
          }
        }
      val = (float)(scale * acc);
    }
    coef[off + e] = val;
  }
}

// ---------------------------------------------------------------------------
// Main kernel. Block = 128 threads <-> 16 low-res pixels (one row chunk).
// Stage: x halo 3x18 pixels into LDS (packed 28-word layout, pads zeroed).
// Work (112 thr = 16 p x 7 kq): per j, M_j quad = sum_i C[i][j][kq] x_p[i]
//   (C streamed from global), then z[nb] += x_nb[j] * M_j (z in registers).
// Combine: per subpixel, out = A00*z[4]+A01*z[c]+A10*z[r]+A11*z[d] + x_p,
//   written to LDS staging; epilogue does coalesced float4 global stores.
// ---------------------------------------------------------------------------

static __device__ __forceinline__ void fma4(float4& a, const float4 c, const float s) {
  a.x = fmaf(c.x, s, a.x); a.y = fmaf(c.y, s, a.y);
  a.z = fmaf(c.z, s, a.z); a.w = fmaf(c.w, s, a.w);
}

__global__ __launch_bounds__(128, 2) void eqconv_main(
    const float* __restrict__ f4, const float* __restrict__ f6,
    const float* __restrict__ sw, const float* __restrict__ coef,
    float* __restrict__ out) {
  __shared__ float xh[3*18*28];   // 6048 B
  __shared__ float o4s[4*576];    // 9216 B
  __shared__ float o6s[4*832];    // 13312 B

  const int tid = threadIdx.x;
  const int ry  = blockIdx.x >> 3;
  const int cx0 = (blockIdx.x & 7) * 16;

  // ---- stage x halo ----
  for (int e = tid; e < 1188; e += 128) {      // 3*18*22
    int r = e / 396, rem = e - r*396;
    int c = rem / 22, w = rem - c*22;
    int rr = min(127, max(0, ry - 1 + r));
    int cc = min(127, max(0, cx0 - 1 + c));
    float v = (w < 9) ? f4[(rr*128 + cc)*9 + w] : f6[(rr*128 + cc)*13 + (w - 9)];
    xh[(r*18 + c)*28 + (w < 9 ? w : w + 3)] = v;
  }
  for (int e = tid; e < 324; e += 128) {       // zero pad slots 9,10,11,25,26,27
    int pix = e / 6, s = e - pix*6;
    xh[pix*28 + (s < 3 ? 9 + s : 22 + s)] = 0.f;
  }
  __syncthreads();

  if (tid < 112) {
    const int kq  = tid >> 4;        // 0..6 (wave-group-major for coalesced C loads)
    const int p   = tid & 15;
    const int kc4 = (kq < 3) ? 1 : 0;
    const int kqc = kc4 ? kq : kq - 3;

    // center pixel x (packed quads; pads are zero)
    const float* xc = &xh[(18 + 1 + p) * 28];
    float4 xq0 = *(const float4*)(xc +  0);
    float4 xq1 = *(const float4*)(xc +  4);
    float4 xq2 = *(const float4*)(xc +  8);
    float4 xq3 = *(const float4*)(xc + 12);
    float4 xq4 = *(const float4*)(xc + 16);
    float4 xq5 = *(const float4*)(xc + 20);
    float4 xq6 = *(const float4*)(xc + 24);
    const float xv[22] = {xq0.x,xq0.y,xq0.z,xq0.w, xq1.x,xq1.y,xq1.z,xq1.w, xq2.x,
                          xq3.x,xq3.y,xq3.z,xq3.w, xq4.x,xq4.y,xq4.z,xq4.w,
                          xq5.x,xq5.y,xq5.z,xq5.w, xq6.x};

    const int ncp  = kc4 ? 12 : 16;
    const int strA = kc4 ? 108 : 144;   // a-stride for lb=4 classes (9*ncp)
    const int strB = kc4 ? 156 : 208;   // a-stride for lb=6 classes (13*ncp)
    const float* cA4 = coef + (kc4 ? 0     : 972)   + 4*kqc;  // (la4,lb4,lc)
    const float* cA6 = coef + (kc4 ? 5544  : 6948)  + 4*kqc;  // (la6,lb4,lc)
    const float* cB4 = coef + (kc4 ? 2268  : 3672)  + 4*kqc;  // (la4,lb6,lc)
    const float* cB6 = coef + (kc4 ? 8820  : 10848) + 4*kqc;  // (la6,lb6,lc)

    float4 z[9];
#pragma unroll
    for (int nb = 0; nb < 9; ++nb) z[nb] = make_float4(0.f, 0.f, 0.f, 0.f);

    int nbo[9];
#pragma unroll
    for (int rs = 0; rs < 3; ++rs)
#pragma unroll
      for (int cs = 0; cs < 3; ++cs)
        nbo[rs*3 + cs] = (rs*18 + p + cs) * 28;

    // lb = 4 (j = 0..8), packed slot = j
#pragma unroll
    for (int j = 0; j < 9; ++j) {
      float4 m = make_float4(0.f, 0.f, 0.f, 0.f);
#pragma unroll
      for (int i = 0; i < 9; ++i)  fma4(m, *(const float4*)(cA4 + j*ncp + i*strA), xv[i]);
#pragma unroll
      for (int i = 0; i < 13; ++i) fma4(m, *(const float4*)(cA6 + j*ncp + i*strA), xv[9 + i]);
#pragma unroll
      for (int nb = 0; nb < 9; ++nb) fma4(z[nb], m, xh[nbo[nb] + j]);
    }
    // lb = 6 (j = 0..12), packed slot = 12 + j
#pragma unroll
    for (int j = 0; j < 13; ++j) {
      float4 m = make_float4(0.f, 0.f, 0.f, 0.f);
#pragma unroll
      for (int i = 0; i < 9; ++i)  fma4(m, *(const float4*)(cB4 + j*ncp + i*strB), xv[i]);
#pragma unroll
      for (int i = 0; i < 13; ++i) fma4(m, *(const float4*)(cB6 + j*ncp + i*strB), xv[9 + i]);
#pragma unroll
      for (int nb = 0; nb < 9; ++nb) fma4(z[nb], m, xh[nbo[nb] + 12 + j]);
    }

    // ---- combine per subpixel ----
    const float s00 = sw[0], s01 = sw[1], s02 = sw[2];
    const float s10 = sw[3], s11 = sw[4], s12 = sw[5];
    const float s20 = sw[6], s21 = sw[7], s22 = sw[8];
    const float swm[9] = {s00,s01,s02,s10,s11,s12,s20,s21,s22};

    const float4 xr = (kq == 0) ? xq0 : (kq == 1) ? xq1 : (kq == 2) ? xq2 :
                      (kq == 3) ? xq3 : (kq == 4) ? xq4 : (kq == 5) ? xq5 : xq6;
    const int cx = cx0 + p;
    const float er0 = (ry != 0)   ? 1.f : 0.f;
    const float er2 = (ry != 127) ? 1.f : 0.f;
    const float ec0 = (cx != 0)   ? 1.f : 0.f;
    const float ec2 = (cx != 127) ? 1.f : 0.f;

#pragma unroll
    for (int sub = 0; sub < 16; ++sub) {
      const int dy = sub >> 2, dx = sub & 3;
      float A00 = 0.f, A01 = 0.f, A10 = 0.f, A11 = 0.f;
#pragma unroll
      for (int t9 = 0; t9 < 9; ++t9) {
        const int ddy = t9 / 3, ddx = t9 % 3;
        const float wr = (ddy == 0) ? ((dy == 0) ? er0 : 0.f)
                                    : ((ddy == 2) ? ((dy == 3) ? er2 : 0.f) : 0.f);
        const float wc = (ddx == 0) ? ((dx == 0) ? ec0 : 0.f)
                                    : ((ddx == 2) ? ((dx == 3) ? ec2 : 0.f) : 0.f);
        const float s = swm[t9];
        A00 += (1.f - wr) * (1.f - wc) * s;
        A01 += (1.f - wr) * wc * s;
        A10 += wr * (1.f - wc) * s;
        A11 += wr * wc * s;
      }
      const int cnb = (dx == 0) ? 3 : 5;
      const int rnb = (dy == 0) ? 1 : 7;
      const int dnb = ((dy == 0) ? 0 : 6) + ((dx == 0) ? 0 : 2);

      float4 o;
      o.x = fmaf(A00, z[4].x, fmaf(A01, z[cnb].x, fmaf(A10, z[rnb].x, fmaf(A11, z[dnb].x, xr.x))));
      o.y = fmaf(A00, z[4].y, fmaf(A01, z[cnb].y, fmaf(A10, z[rnb].y, fmaf(A11, z[dnb].y, xr.y))));
      o.z = fmaf(A00, z[4].z, fmaf(A01, z[cnb].z, fmaf(A10, z[rnb].z, fmaf(A11, z[dnb].z, xr.z))));
      o.w = fmaf(A00, z[4].w, fmaf(A01, z[cnb].w, fmaf(A10, z[rnb].w, fmaf(A11, z[dnb].w, xr.w))));

      const int pc = p*4 + dx;
      if (kq < 2) {
        const int b = dy*576 + pc*9 + 4*kq;
        o4s[b] = o.x; o4s[b+1] = o.y; o4s[b+2] = o.z; o4s[b+3] = o.w;
      } else if (kq == 2) {
        o4s[dy*576 + pc*9 + 8] = o.x;
      } else if (kq < 6) {
        const int b = dy*832 + pc*13 + 4*(kq - 3);
        o6s[b] = o.x; o6s[b+1] = o.y; o6s[b+2] = o.z; o6s[b+3] = o.w;
      } else {
        o6s[dy*832 + pc*13 + 12] = o.x;
      }
    }
  }
  __syncthreads();

  // ---- epilogue: coalesced float4 stores ----
  const int rb4 = ((ry*4)*512 + cx0*4) * 9;
  for (int q = tid; q < 576; q += 128) {
    int row = q / 144, col = q - row*144;
    *(float4*)(out + rb4 + row*(512*9) + 4*col) = *(const float4*)(o4s + row*576 + 4*col);
  }
  const int rb6 = NPIX*9 + ((ry*4)*512 + cx0*4) * 13;
  for (int q = tid; q < 832; q += 128) {
    int row = q / 208, col = q - row*208;
    *(float4*)(out + rb6 + row*(512*13) + 4*col) = *(const float4*)(o6s + row*832 + 4*col);
  }
}

extern "C" void kernel_launch(void* const* d_in, const int* in_sizes, int n_in,
                              void* d_out, int out_size, void* d_ws, size_t ws_size,
                              hipStream_t stream) {
  const float* f4  = (const float*)d_in[0];
  const float* f6  = (const float*)d_in[1];
  const float* sw  = (const float*)d_in[2];
  const float* tpw = (const float*)d_in[3];
  float* coef = (float*)d_ws;
  float* out  = (float*)d_out;

  hipLaunchKernelGGL(w3j_init, dim3(8), dim3(256), 0, stream, tpw, coef);
  hipLaunchKernelGGL(eqconv_main, dim3(1024), dim3(128), 0, stream,
                     f4, f6, sw, coef, out);
}

// Round 5
// 902.116 us; speedup vs baseline: 1.0189x; 1.0189x over previous
//
#include <hip/hip_runtime.h>

#define NPIX (512*512)

// ---------------------------------------------------------------------------
// Init kernel: coef[path][a][b][kq] = 0.5 * tp_w * Cr  (padded k-runs: 12/16).
// Path offsets (floats): {0,972,2268,3672,5544,6948,8820,10848}, 13552 total.
// path index p: la = p&4?6:4, lb = p&2?6:4, lc = p&1?6:4.
// layout per path: [a (2la+1)][b (2lb+1)][kq (ncp=12|16)], pads (c>=nc) are 0.
// ---------------------------------------------------------------------------

static __device__ __forceinline__ int qcol(int l, int c, int* row, double* re, double* im) {
  const double S = 0.70710678118654752440;
  int p = c - l;
  if (p == 0) { row[0] = l; re[0] = 1.0; im[0] = 0.0; return 1; }
  if (p > 0) {
    row[0] = l - p; re[0] = S;                 im[0] = 0.0;
    row[1] = l + p; re[1] = (p & 1) ? -S : S;  im[1] = 0.0;
    return 2;
  }
  int a = -p;
  row[0] = l - a; re[0] = 0.0; im[0] = -S;
  row[1] = l + a; re[1] = 0.0; im[1] = (a & 1) ? -S : S;
  return 2;
}

__global__ void w3j_init(const float* __restrict__ tpw, float* __restrict__ coef) {
  __shared__ double sC[13*13*13];
  __shared__ double sfact[20];
  const int p = blockIdx.x;
  const int la = (p & 4) ? 6 : 4, lb = (p & 2) ? 6 : 4, lc = (p & 1) ? 6 : 4;
  const int na = 2*la+1, nb = 2*lb+1, nc = 2*lc+1, ncp = (nc + 3) & ~3;
  if (threadIdx.x == 0) {
    double f = 1.0; sfact[0] = 1.0;
    for (int i = 1; i < 20; ++i) { f *= (double)i; sfact[i] = f; }
  }
  int off = 0;
  for (int q = 0; q < p; ++q)
    off += ((q&4)?13:9) * ((q&2)?13:9) * ((q&1)?16:12);
  for (int e = threadIdx.x; e < na*nb*nc; e += blockDim.x) sC[e] = 0.0;
  __syncthreads();
  for (int e = threadIdx.x; e < na*nb; e += blockDim.x) {
    int i = e / nb, j = e % nb;
    int m1 = i - la, m2 = j - lb, m3 = m1 + m2;
    if (m3 < -lc || m3 > lc) continue;
    double pre = sqrt((2.0*lc + 1.0) * sfact[lc+la-lb] * sfact[lc-la+lb] * sfact[la+lb-lc] / sfact[la+lb+lc+1]);
    pre *= sqrt(sfact[lc+m3]*sfact[lc-m3]*sfact[la-m1]*sfact[la+m1]*sfact[lb-m2]*sfact[lb+m2]);
    double s = 0.0;
    for (int k = 0; k <= la + lb - lc; ++k) {
      int d2 = la - m1 - k, d3 = lb + m2 - k, d4 = lc - lb + m1 + k, d5 = lc - la - m2 + k;
      if (d2 < 0 || d3 < 0 || d4 < 0 || d5 < 0) continue;
      s += ((k & 1) ? -1.0 : 1.0) /
           (sfact[k]*sfact[la+lb-lc-k]*sfact[d2]*sfact[d3]*sfact[d4]*sfact[d5]);
    }
    sC[(i*nb + j)*nc + (lc + m3)] = pre * s;
  }
  __syncthreads();
  const double PH = (((la/2)&1)?-1.0:1.0)*(((lb/2)&1)?-1.0:1.0)*(((lc/2)&1)?-1.0:1.0);
  const double scale = 0.5 * (double)tpw[p] * PH;
  for (int e = threadIdx.x; e < na*nb*ncp; e += blockDim.x) {
    int a = e / (nb*ncp), rem = e % (nb*ncp), b = rem / ncp, c = rem % ncp;
    float val = 0.0f;
    if (c < nc) {
      int r1[2]; double u1r[2], u1i[2]; int n1 = qcol(la, a, r1, u1r, u1i);
      int r2[2]; double u2r[2], u2i[2]; int n2 = qcol(lb, b, r2, u2r, u2i);
      int r3[2]; double u3r[2], u3i[2]; int n3 = qcol(lc, c, r3, u3r, u3i);
      double acc = 0.0;
      for (int u = 0; u < n1; ++u)
        for (int v = 0; v < n2; ++v) {
          double Rr = u1r[u]*u2r[v] - u1i[u]*u2i[v];
          double Ri = u1r[u]*u2i[v] + u1i[u]*u2r[v];
          for (int w = 0; w < n3; ++w) {
            double cv = sC[(r1[u]*nb + r2[v])*nc + r3[w]];
            acc += (Rr*u3r[w] + Ri*u3i[w]) * cv;
          }
        }
      val = (float)(scale * acc);
    }
    coef[off + e] = val;
  }
}

// ---------------------------------------------------------------------------
// Main kernel. Block = 128 threads <-> 16 low-res pixels (one row chunk).
// NO register array is ever runtime-indexed (round-4 lesson: z[cnb] sent z to
// scratch -> 1.8 GB of spill traffic). z is nine NAMED float4s; subpixel
// neighbor selection is a combine<DY,DX> template instantiated 16 times.
// ---------------------------------------------------------------------------

static __device__ __forceinline__ void fma4(float4& a, const float4 c, const float s) {
  a.x = fmaf(c.x, s, a.x); a.y = fmaf(c.y, s, a.y);
  a.z = fmaf(c.z, s, a.z); a.w = fmaf(c.w, s, a.w);
}

template<int DY, int DX>
static __device__ __forceinline__ float4 combine(
    float4 z0, float4 z1, float4 z2, float4 z3, float4 z4,
    float4 z5, float4 z6, float4 z7, float4 z8,
    float s0, float s1, float s2, float s3, float s4,
    float s5, float s6, float s7, float s8,
    float er0, float er2, float ec0, float ec2, float4 xr) {
  float A00 = 0.f, A01 = 0.f, A10 = 0.f, A11 = 0.f;
  const float sArr[9] = {s0, s1, s2, s3, s4, s5, s6, s7, s8};
#pragma unroll
  for (int t9 = 0; t9 < 9; ++t9) {
    const int ddy = t9 / 3, ddx = t9 % 3;
    const float wr = (ddy == 0) ? ((DY == 0) ? er0 : 0.f)
                                : ((ddy == 2) ? ((DY == 3) ? er2 : 0.f) : 0.f);
    const float wc = (ddx == 0) ? ((DX == 0) ? ec0 : 0.f)
                                : ((ddx == 2) ? ((DX == 3) ? ec2 : 0.f) : 0.f);
    const float s = sArr[t9];
    A00 += (1.f - wr) * (1.f - wc) * s;
    A01 += (1.f - wr) * wc * s;
    A10 += wr * (1.f - wc) * s;
    A11 += wr * wc * s;
  }
  const float4 zcol = (DX == 0) ? z3 : z5;                               // compile-time
  const float4 zrow = (DY == 0) ? z1 : z7;                               // compile-time
  const float4 zdia = (DY == 0) ? ((DX == 0) ? z0 : z2)
                                : ((DX == 0) ? z6 : z8);                 // compile-time
  float4 o;
  o.x = fmaf(A00, z4.x, fmaf(A01, zcol.x, fmaf(A10, zrow.x, fmaf(A11, zdia.x, xr.x))));
  o.y = fmaf(A00, z4.y, fmaf(A01, zcol.y, fmaf(A10, zrow.y, fmaf(A11, zdia.y, xr.y))));
  o.z = fmaf(A00, z4.z, fmaf(A01, zcol.z, fmaf(A10, zrow.z, fmaf(A11, zdia.z, xr.z))));
  o.w = fmaf(A00, z4.w, fmaf(A01, zcol.w, fmaf(A10, zrow.w, fmaf(A11, zdia.w, xr.w))));
  return o;
}

__global__ __launch_bounds__(128, 2) void eqconv_main(
    const float* __restrict__ f4, const float* __restrict__ f6,
    const float* __restrict__ sw, const float* __restrict__ coef,
    float* __restrict__ out) {
  __shared__ float xh[3*18*28];   // 6048 B
  __shared__ float o4s[4*576];    // 9216 B
  __shared__ float o6s[4*832];    // 13312 B

  const int tid = threadIdx.x;
  const int ry  = blockIdx.x >> 3;
  const int cx0 = (blockIdx.x & 7) * 16;

  // ---- stage x halo (packed 28-word layout; pads zeroed) ----
  for (int e = tid; e < 1188; e += 128) {      // 3*18*22
    int r = e / 396, rem = e - r*396;
    int c = rem / 22, w = rem - c*22;
    int rr = min(127, max(0, ry - 1 + r));
    int cc = min(127, max(0, cx0 - 1 + c));
    float v = (w < 9) ? f4[(rr*128 + cc)*9 + w] : f6[(rr*128 + cc)*13 + (w - 9)];
    xh[(r*18 + c)*28 + (w < 9 ? w : w + 3)] = v;
  }
  for (int e = tid; e < 324; e += 128) {       // zero pad slots 9,10,11,25,26,27
    int pix = e / 6, s = e - pix*6;
    xh[pix*28 + (s < 3 ? 9 + s : 22 + s)] = 0.f;
  }
  __syncthreads();

  if (tid < 112) {
    const int kq  = tid >> 4;        // 0..6
    const int p   = tid & 15;
    const int kc4 = (kq < 3) ? 1 : 0;
    const int kqc = kc4 ? kq : kq - 3;

    const float* xc = &xh[(18 + 1 + p) * 28];
    float4 xq0 = *(const float4*)(xc +  0);
    float4 xq1 = *(const float4*)(xc +  4);
    float4 xq2 = *(const float4*)(xc +  8);
    float4 xq3 = *(const float4*)(xc + 12);
    float4 xq4 = *(const float4*)(xc + 16);
    float4 xq5 = *(const float4*)(xc + 20);
    float4 xq6 = *(const float4*)(xc + 24);
    const float xv[22] = {xq0.x,xq0.y,xq0.z,xq0.w, xq1.x,xq1.y,xq1.z,xq1.w, xq2.x,
                          xq3.x,xq3.y,xq3.z,xq3.w, xq4.x,xq4.y,xq4.z,xq4.w,
                          xq5.x,xq5.y,xq5.z,xq5.w, xq6.x};

    const int ncp  = kc4 ? 12 : 16;
    const int strA = kc4 ? 108 : 144;   // a-stride, lb=4 tables (9*ncp)
    const int strB = kc4 ? 156 : 208;   // a-stride, lb=6 tables (13*ncp)
    const float* cA4 = coef + (kc4 ? 0     : 972)   + 4*kqc;  // (la4,lb4,lc)
    const float* cA6 = coef + (kc4 ? 5544  : 6948)  + 4*kqc;  // (la6,lb4,lc)
    const float* cB4 = coef + (kc4 ? 2268  : 3672)  + 4*kqc;  // (la4,lb6,lc)
    const float* cB6 = coef + (kc4 ? 8820  : 10848) + 4*kqc;  // (la6,lb6,lc)

    // nine NAMED z accumulators + nine NAMED neighbor offsets
    float4 z0 = make_float4(0.f,0.f,0.f,0.f), z1 = z0, z2 = z0, z3 = z0,
           z4 = z0, z5 = z0, z6 = z0, z7 = z0, z8 = z0;
    const int o0 = (0*18 + p + 0)*28, o1 = (0*18 + p + 1)*28, o2 = (0*18 + p + 2)*28;
    const int o3 = (1*18 + p + 0)*28, o4 = (1*18 + p + 1)*28, o5 = (1*18 + p + 2)*28;
    const int o6 = (2*18 + p + 0)*28, o7 = (2*18 + p + 1)*28, o8 = (2*18 + p + 2)*28;

#define JSTEP(JS, CB4, CB6, STR) { \
    float4 m = make_float4(0.f,0.f,0.f,0.f); \
    _Pragma("unroll") \
    for (int i = 0; i < 9; ++i)  fma4(m, *(const float4*)((CB4) + i*(STR)), xv[i]); \
    _Pragma("unroll") \
    for (int i = 0; i < 13; ++i) fma4(m, *(const float4*)((CB6) + i*(STR)), xv[9+i]); \
    fma4(z0, m, xh[o0 + (JS)]); fma4(z1, m, xh[o1 + (JS)]); fma4(z2, m, xh[o2 + (JS)]); \
    fma4(z3, m, xh[o3 + (JS)]); fma4(z4, m, xh[o4 + (JS)]); fma4(z5, m, xh[o5 + (JS)]); \
    fma4(z6, m, xh[o6 + (JS)]); fma4(z7, m, xh[o7 + (JS)]); fma4(z8, m, xh[o8 + (JS)]); }

#pragma unroll
    for (int j = 0; j < 9; ++j)  JSTEP(j,      cA4 + j*ncp, cA6 + j*ncp, strA)
#pragma unroll
    for (int j = 0; j < 13; ++j) JSTEP(12 + j, cB4 + j*ncp, cB6 + j*ncp, strB)
#undef JSTEP

    const float s0 = sw[0], s1 = sw[1], s2 = sw[2];
    const float s3 = sw[3], s4 = sw[4], s5 = sw[5];
    const float s6 = sw[6], s7 = sw[7], s8 = sw[8];

    const float4 xr = (kq == 0) ? xq0 : (kq == 1) ? xq1 : (kq == 2) ? xq2 :
                      (kq == 3) ? xq3 : (kq == 4) ? xq4 : (kq == 5) ? xq5 : xq6;
    const int cx = cx0 + p;
    const float er0 = (ry != 0)   ? 1.f : 0.f;
    const float er2 = (ry != 127) ? 1.f : 0.f;
    const float ec0 = (cx != 0)   ? 1.f : 0.f;
    const float ec2 = (cx != 127) ? 1.f : 0.f;

    // store helper (LDS staging; runtime kq selects the slice)
    auto store_o = [&](int dy, int dx, float4 o) {
      const int pc = p*4 + dx;
      if (kq < 2) {
        const int b = dy*576 + pc*9 + 4*kq;
        o4s[b] = o.x; o4s[b+1] = o.y; o4s[b+2] = o.z; o4s[b+3] = o.w;
      } else if (kq == 2) {
        o4s[dy*576 + pc*9 + 8] = o.x;
      } else if (kq < 6) {
        const int b = dy*832 + pc*13 + 4*(kq - 3);
        o6s[b] = o.x; o6s[b+1] = o.y; o6s[b+2] = o.z; o6s[b+3] = o.w;
      } else {
        o6s[dy*832 + pc*13 + 12] = o.x;
      }
    };

#define DOSUB(DY, DX) store_o(DY, DX, combine<DY, DX>( \
    z0, z1, z2, z3, z4, z5, z6, z7, z8, \
    s0, s1, s2, s3, s4, s5, s6, s7, s8, \
    er0, er2, ec0, ec2, xr))
    DOSUB(0,0); DOSUB(0,1); DOSUB(0,2); DOSUB(0,3);
    DOSUB(1,0); DOSUB(1,1); DOSUB(1,2); DOSUB(1,3);
    DOSUB(2,0); DOSUB(2,1); DOSUB(2,2); DOSUB(2,3);
    DOSUB(3,0); DOSUB(3,1); DOSUB(3,2); DOSUB(3,3);
#undef DOSUB
  }
  __syncthreads();

  // ---- epilogue: coalesced float4 stores ----
  const int rb4 = ((ry*4)*512 + cx0*4) * 9;
  for (int q = tid; q < 576; q += 128) {
    int row = q / 144, col = q - row*144;
    *(float4*)(out + rb4 + row*(512*9) + 4*col) = *(const float4*)(o4s + row*576 + 4*col);
  }
  const int rb6 = NPIX*9 + ((ry*4)*512 + cx0*4) * 13;
  for (int q = tid; q < 832; q += 128) {
    int row = q / 208, col = q - row*208;
    *(float4*)(out + rb6 + row*(512*13) + 4*col) = *(const float4*)(o6s + row*832 + 4*col);
  }
}

extern "C" void kernel_launch(void* const* d_in, const int* in_sizes, int n_in,
                              void* d_out, int out_size, void* d_ws, size_t ws_size,
                              hipStream_t stream) {
  const float* f4  = (const float*)d_in[0];
  const float* f6  = (const float*)d_in[1];
  const float* sw  = (const float*)d_in[2];
  const float* tpw = (const float*)d_in[3];
  float* coef = (float*)d_ws;
  float* out  = (float*)d_out;

  hipLaunchKernelGGL(w3j_init, dim3(8), dim3(256), 0, stream, tpw, coef);
  hipLaunchKernelGGL(eqconv_main, dim3(1024), dim3(128), 0, stream,
                     f4, f6, sw, coef, out);
}

// Round 7
// 48.118 us; speedup vs baseline: 19.1018x; 18.7478x over previous
//
#include <hip/hip_runtime.h>

#define NPIX (512*512)

// ---------------------------------------------------------------------------
// Init kernel: coef[path][a][b][kq] = 0.5 * tp_w * Cr  (padded k-runs: 12/16).
// Path offsets (floats): {0,972,2268,3672,5544,6948,8820,10848}, 13552 total.
// path index p: la = p&4?6:4, lb = p&2?6:4, lc = p&1?6:4.
// layout per path: [a (2la+1)][b (2lb+1)][kq (ncp=12|16)], pads (c>=nc) are 0.
// ---------------------------------------------------------------------------

static __device__ __forceinline__ int qcol(int l, int c, int* row, double* re, double* im) {
  const double S = 0.70710678118654752440;
  int p = c - l;
  if (p == 0) { row[0] = l; re[0] = 1.0; im[0] = 0.0; return 1; }
  if (p > 0) {
    row[0] = l - p; re[0] = S;                 im[0] = 0.0;
    row[1] = l + p; re[1] = (p & 1) ? -S : S;  im[1] = 0.0;
    return 2;
  }
  int a = -p;
  row[0] = l - a; re[0] = 0.0; im[0] = -S;
  row[1] = l + a; re[1] = 0.0; im[1] = (a & 1) ? -S : S;
  return 2;
}

__global__ void w3j_init(const float* __restrict__ tpw, float* __restrict__ coef) {
  __shared__ double sC[13*13*13];
  __shared__ double sfact[20];
  const int p = blockIdx.x;
  const int la = (p & 4) ? 6 : 4, lb = (p & 2) ? 6 : 4, lc = (p & 1) ? 6 : 4;
  const int na = 2*la+1, nb = 2*lb+1, nc = 2*lc+1, ncp = (nc + 3) & ~3;
  if (threadIdx.x == 0) {
    double f = 1.0; sfact[0] = 1.0;
    for (int i = 1; i < 20; ++i) { f *= (double)i; sfact[i] = f; }
  }
  int off = 0;
  for (int q = 0; q < p; ++q)
    off += ((q&4)?13:9) * ((q&2)?13:9) * ((q&1)?16:12);
  for (int e = threadIdx.x; e < na*nb*nc; e += blockDim.x) sC[e] = 0.0;
  __syncthreads();
  for (int e = threadIdx.x; e < na*nb; e += blockDim.x) {
    int i = e / nb, j = e % nb;
    int m1 = i - la, m2 = j - lb, m3 = m1 + m2;
    if (m3 < -lc || m3 > lc) continue;
    double pre = sqrt((2.0*lc + 1.0) * sfact[lc+la-lb] * sfact[lc-la+lb] * sfact[la+lb-lc] / sfact[la+lb+lc+1]);
    pre *= sqrt(sfact[lc+m3]*sfact[lc-m3]*sfact[la-m1]*sfact[la+m1]*sfact[lb-m2]*sfact[lb+m2]);
    double s = 0.0;
    for (int k = 0; k <= la + lb - lc; ++k) {
      int d2 = la - m1 - k, d3 = lb + m2 - k, d4 = lc - lb + m1 + k, d5 = lc - la - m2 + k;
      if (d2 < 0 || d3 < 0 || d4 < 0 || d5 < 0) continue;
      s += ((k & 1) ? -1.0 : 1.0) /
           (sfact[k]*sfact[la+lb-lc-k]*sfact[d2]*sfact[d3]*sfact[d4]*sfact[d5]);
    }
    sC[(i*nb + j)*nc + (lc + m3)] = pre * s;
  }
  __syncthreads();
  const double PH = (((la/2)&1)?-1.0:1.0)*(((lb/2)&1)?-1.0:1.0)*(((lc/2)&1)?-1.0:1.0);
  const double scale = 0.5 * (double)tpw[p] * PH;
  for (int e = threadIdx.x; e < na*nb*ncp; e += blockDim.x) {
    int a = e / (nb*ncp), rem = e % (nb*ncp), b = rem / ncp, c = rem % ncp;
    float val = 0.0f;
    if (c < nc) {
      int r1[2]; double u1r[2], u1i[2]; int n1 = qcol(la, a, r1, u1r, u1i);
      int r2[2]; double u2r[2], u2i[2]; int n2 = qcol(lb, b, r2, u2r, u2i);
      int r3[2]; double u3r[2], u3i[2]; int n3 = qcol(lc, c, r3, u3r, u3i);
      double acc = 0.0;
      for (int u = 0; u < n1; ++u)
        for (int v = 0; v < n2; ++v) {
          double Rr = u1r[u]*u2r[v] - u1i[u]*u2i[v];
          double Ri = u1r[u]*u2i[v] + u1i[u]*u2r[v];
          for (int w = 0; w < n3; ++w) {
            double cv = sC[(r1[u]*nb + r2[v])*nc + r3[w]];
            acc += (Rr*u3r[w] + Ri*u3i[w]) * cv;
          }
        }
      val = (float)(scale * acc);
    }
    coef[off + e] = val;
  }
}

// ---------------------------------------------------------------------------
// Main kernel. 256 thr, 16 low-res pixels/block, grid 1024.
//  P1 (154 thr, entry=(j,kq)): C loaded ONCE into cR[22] regs (no load streams
//      -> no spill, r2-proven), x via LDS xT broadcast, M -> LDS.
//  P2 (112 thr, (p,kq)): m[22] quads from LDS once, z[9] in regs from packed
//      halo quads; barrier; templated combine -> LDS o-staging (aliased on M).
//  Epilogue: coalesced float4 stores.
// ---------------------------------------------------------------------------

static __device__ __forceinline__ void fma4(float4& a, const float4 c, const float s) {
  a.x = fmaf(c.x, s, a.x); a.y = fmaf(c.y, s, a.y);
  a.z = fmaf(c.z, s, a.z); a.w = fmaf(c.w, s, a.w);
}

template<int DY, int DX>
static __device__ __forceinline__ float4 combine(
    const float4* z,
    float s0, float s1, float s2, float s3, float s4,
    float s5, float s6, float s7, float s8,
    float er0, float er2, float ec0, float ec2, float4 xr) {
  float A00 = 0.f, A01 = 0.f, A10 = 0.f, A11 = 0.f;
  const float sArr[9] = {s0, s1, s2, s3, s4, s5, s6, s7, s8};
#pragma unroll
  for (int t9 = 0; t9 < 9; ++t9) {
    const int ddy = t9 / 3, ddx = t9 % 3;
    const float wr = (ddy == 0) ? ((DY == 0) ? er0 : 0.f)
                                : ((ddy == 2) ? ((DY == 3) ? er2 : 0.f) : 0.f);
    const float wc = (ddx == 0) ? ((DX == 0) ? ec0 : 0.f)
                                : ((ddx == 2) ? ((DX == 3) ? ec2 : 0.f) : 0.f);
    const float s = sArr[t9];
    A00 += (1.f - wr) * (1.f - wc) * s;
    A01 += (1.f - wr) * wc * s;
    A10 += wr * (1.f - wc) * s;
    A11 += wr * wc * s;
  }
  const float4 zc = z[4];
  const float4 zcol = (DX == 0) ? z[3] : z[5];
  const float4 zrow = (DY == 0) ? z[1] : z[7];
  const float4 zdia = (DY == 0) ? ((DX == 0) ? z[0] : z[2])
                                : ((DX == 0) ? z[6] : z[8]);
  float4 o;
  o.x = fmaf(A00, zc.x, fmaf(A01, zcol.x, fmaf(A10, zrow.x, fmaf(A11, zdia.x, xr.x))));
  o.y = fmaf(A00, zc.y, fmaf(A01, zcol.y, fmaf(A10, zrow.y, fmaf(A11, zdia.y, xr.y))));
  o.z = fmaf(A00, zc.z, fmaf(A01, zcol.z, fmaf(A10, zrow.z, fmaf(A11, zdia.z, xr.z))));
  o.w = fmaf(A00, zc.w, fmaf(A01, zcol.w, fmaf(A10, zrow.w, fmaf(A11, zdia.w, xr.w))));
  return o;
}

__global__ __launch_bounds__(256, 2) void eqconv_main(
    const float* __restrict__ f4, const float* __restrict__ f6,
    const float* __restrict__ sw, const float* __restrict__ coef,
    float* __restrict__ out) {
  __shared__ float Mf[16 * 620];   // 39680 B; after P2, aliased as o4s/o6s staging
  __shared__ float xh[3*18*28];    // 6048 B packed halo
  __shared__ float xT[22*16];      // 1408 B transposed center row

  const int tid = threadIdx.x;
  const int ry  = blockIdx.x >> 3;
  const int cx0 = (blockIdx.x & 7) * 16;

  // ---- stage halo (packed-28; pads zeroed) + transposed center row ----
  for (int e = tid; e < 1188; e += 256) {      // 3*18*22
    int r = e / 396, rem = e - r*396;
    int c = rem / 22, w = rem - c*22;
    int rr = min(127, max(0, ry - 1 + r));
    int cc = min(127, max(0, cx0 - 1 + c));
    float v = (w < 9) ? f4[(rr*128 + cc)*9 + w] : f6[(rr*128 + cc)*13 + (w - 9)];
    xh[(r*18 + c)*28 + (w < 9 ? w : w + 3)] = v;
  }
  for (int e = tid; e < 324; e += 256) {       // zero pad slots 9,10,11,25,26,27
    int pix = e / 6, s = e - pix*6;
    xh[pix*28 + (s < 3 ? 9 + s : 22 + s)] = 0.f;
  }
  for (int e = tid; e < 352; e += 256) {       // xT[c][p]  (FIX: was if(tid<352) with 256 threads)
    int c = e >> 4, p = e & 15;
    int pix = ry*128 + cx0 + p;
    xT[c*16 + p] = (c < 9) ? f4[pix*9 + c] : f6[pix*13 + (c - 9)];
  }
  __syncthreads();

  // ---------------- P1: M = C . x  (C once into regs) ----------------
  if (tid < 154) {
    int cls, jj, kqc;
    if (tid < 27)       { cls = 0; jj = tid / 3;         kqc = tid % 3; }
    else if (tid < 63)  { cls = 1; jj = (tid - 27) / 4;  kqc = (tid - 27) % 4; }
    else if (tid < 102) { cls = 2; jj = (tid - 63) / 3;  kqc = (tid - 63) % 3; }
    else                { cls = 3; jj = (tid - 102) / 4; kqc = (tid - 102) % 4; }
    const int ncp  = (cls == 0 || cls == 2) ? 12 : 16;
    const int str  = (cls == 0) ? 108 : (cls == 1) ? 144 : (cls == 2) ? 156 : 208;
    const int off4 = (cls == 0) ? 0    : (cls == 1) ? 972  : (cls == 2) ? 2268 : 3672;
    const int off6 = (cls == 0) ? 5544 : (cls == 1) ? 6948 : (cls == 2) ? 8820 : 10848;
    const int base4 = off4 + jj*ncp + 4*kqc;
    const int base6 = off6 + jj*ncp + 4*kqc;
    const int j   = (cls >= 2) ? 9 + jj : jj;
    const int kqu = (cls == 0 || cls == 2) ? kqc : 3 + kqc;

    float4 cR[22];
#pragma unroll
    for (int i = 0; i < 9; ++i)  cR[i]     = *(const float4*)(coef + base4 + i*str);
#pragma unroll
    for (int i = 0; i < 13; ++i) cR[9 + i] = *(const float4*)(coef + base6 + i*str);

    const int mo = j*28 + kqu*4;
#pragma unroll
    for (int half = 0; half < 2; ++half) {
      float4 acc[8];
#pragma unroll
      for (int p8 = 0; p8 < 8; ++p8) acc[p8] = make_float4(0.f, 0.f, 0.f, 0.f);
#pragma unroll
      for (int i = 0; i < 22; ++i) {
        float4 xa = *(const float4*)(&xT[i*16 + half*8]);
        float4 xb = *(const float4*)(&xT[i*16 + half*8 + 4]);
        fma4(acc[0], cR[i], xa.x); fma4(acc[1], cR[i], xa.y);
        fma4(acc[2], cR[i], xa.z); fma4(acc[3], cR[i], xa.w);
        fma4(acc[4], cR[i], xb.x); fma4(acc[5], cR[i], xb.y);
        fma4(acc[6], cR[i], xb.z); fma4(acc[7], cR[i], xb.w);
      }
#pragma unroll
      for (int p8 = 0; p8 < 8; ++p8)
        *(float4*)(&Mf[(half*8 + p8)*620 + mo]) = acc[p8];
    }
  }
  __syncthreads();

  // ---------------- P2: z[nb] = x_nb^T . M_p  (regs) ----------------
  const int p   = tid >> 3;
  const int kq7 = tid & 7;
  const bool act = (tid < 128) && (kq7 < 7);

  float4 z[9];
#pragma unroll
  for (int nb = 0; nb < 9; ++nb) z[nb] = make_float4(0.f, 0.f, 0.f, 0.f);
  float4 xr = make_float4(0.f, 0.f, 0.f, 0.f);

  if (act) {
    const float* Mp = &Mf[p*620 + 4*kq7];
    float4 m[22];
#pragma unroll
    for (int jx = 0; jx < 22; ++jx) m[jx] = *(const float4*)(Mp + jx*28);

#pragma unroll
    for (int rs = 0; rs < 3; ++rs) {
#pragma unroll
      for (int cs = 0; cs < 3; ++cs) {
        const float* xb = &xh[(rs*18 + p + cs)*28];
        float4 x0 = *(const float4*)(xb);
        float4 x1 = *(const float4*)(xb + 4);
        float4 x2 = *(const float4*)(xb + 8);
        float4 x3 = *(const float4*)(xb + 12);
        float4 x4 = *(const float4*)(xb + 16);
        float4 x5 = *(const float4*)(xb + 20);
        float4 x6 = *(const float4*)(xb + 24);
        float4 t = z[rs*3 + cs];
        fma4(t, m[0],  x0.x); fma4(t, m[1],  x0.y); fma4(t, m[2],  x0.z); fma4(t, m[3],  x0.w);
        fma4(t, m[4],  x1.x); fma4(t, m[5],  x1.y); fma4(t, m[6],  x1.z); fma4(t, m[7],  x1.w);
        fma4(t, m[8],  x2.x);
        fma4(t, m[9],  x3.x); fma4(t, m[10], x3.y); fma4(t, m[11], x3.z); fma4(t, m[12], x3.w);
        fma4(t, m[13], x4.x); fma4(t, m[14], x4.y); fma4(t, m[15], x4.z); fma4(t, m[16], x4.w);
        fma4(t, m[17], x5.x); fma4(t, m[18], x5.y); fma4(t, m[19], x5.z); fma4(t, m[20], x5.w);
        fma4(t, m[21], x6.x);
        z[rs*3 + cs] = t;
      }
    }
    xr = *(const float4*)(&xh[(18 + 1 + p)*28 + 4*kq7]);
  }
  __syncthreads();    // all M reads done; Mf region becomes o-staging

  // ---------------- combine -> LDS staging (aliased on Mf) ----------------
  float* o4s = Mf;            // 4*576  = 2304 floats
  float* o6s = Mf + 2304;     // 4*832  = 3328 floats
  if (act) {
    const float s0 = sw[0], s1 = sw[1], s2 = sw[2];
    const float s3 = sw[3], s4 = sw[4], s5 = sw[5];
    const float s6 = sw[6], s7 = sw[7], s8 = sw[8];
    const int cx = cx0 + p;
    const float er0 = (ry != 0)   ? 1.f : 0.f;
    const float er2 = (ry != 127) ? 1.f : 0.f;
    const float ec0 = (cx != 0)   ? 1.f : 0.f;
    const float ec2 = (cx != 127) ? 1.f : 0.f;

    auto store_o = [&](int dy, int dx, float4 o) {
      const int pc = p*4 + dx;
      if (kq7 < 2) {
        const int b = dy*576 + pc*9 + 4*kq7;
        o4s[b] = o.x; o4s[b+1] = o.y; o4s[b+2] = o.z; o4s[b+3] = o.w;
      } else if (kq7 == 2) {
        o4s[dy*576 + pc*9 + 8] = o.x;
      } else if (kq7 < 6) {
        const int b = dy*832 + pc*13 + 4*(kq7 - 3);
        o6s[b] = o.x; o6s[b+1] = o.y; o6s[b+2] = o.z; o6s[b+3] = o.w;
      } else {
        o6s[dy*832 + pc*13 + 12] = o.x;
      }
    };

#define DOSUB(DY, DX) store_o(DY, DX, \
    combine<DY, DX>(z, s0, s1, s2, s3, s4, s5, s6, s7, s8, er0, er2, ec0, ec2, xr))
    DOSUB(0,0); DOSUB(0,1); DOSUB(0,2); DOSUB(0,3);
    DOSUB(1,0); DOSUB(1,1); DOSUB(1,2); DOSUB(1,3);
    DOSUB(2,0); DOSUB(2,1); DOSUB(2,2); DOSUB(2,3);
    DOSUB(3,0); DOSUB(3,1); DOSUB(3,2); DOSUB(3,3);
#undef DOSUB
  }
  __syncthreads();

  // ---------------- epilogue: coalesced float4 stores ----------------
  const int rb4 = ((ry*4)*512 + cx0*4) * 9;
  for (int q = tid; q < 576; q += 256) {
    int row = q / 144, col = q - row*144;
    *(float4*)(out + rb4 + row*(512*9) + 4*col) = *(const float4*)(o4s + row*576 + 4*col);
  }
  const int rb6 = NPIX*9 + ((ry*4)*512 + cx0*4) * 13;
  for (int q = tid; q < 832; q += 256) {
    int row = q / 208, col = q - row*208;
    *(float4*)(out + rb6 + row*(512*13) + 4*col) = *(const float4*)(o6s + row*832 + 4*col);
  }
}

extern "C" void kernel_launch(void* const* d_in, const int* in_sizes, int n_in,
                              void* d_out, int out_size, void* d_ws, size_t ws_size,
                              hipStream_t stream) {
  const float* f4  = (const float*)d_in[0];
  const float* f6  = (const float*)d_in[1];
  const float* sw  = (const float*)d_in[2];
  const float* tpw = (const float*)d_in[3];
  float* coef = (float*)d_ws;
  float* out  = (float*)d_out;

  hipLaunchKernelGGL(w3j_init, dim3(8), dim3(256), 0, stream, tpw, coef);
  hipLaunchKernelGGL(eqconv_main, dim3(1024), dim3(256), 0, stream,
                     f4, f6, sw, coef, out);
}